// Round 7
// baseline (104.459 us; speedup 1.0000x reference)
//
#include <hip/hip_runtime.h>
#include <math.h>

#define F 1024
#define D 64
#define H 128

typedef float v2f __attribute__((ext_vector_type(2)));

// Prep: A[i][k] = sum_r node[i][r]*W1[r][k] + b1[k]
//       Bt[k][i] = sum_r node[i][r]*W1[64+r][k]
__global__ __launch_bounds__(128) void prep_kernel(
    const float* __restrict__ node, const float* __restrict__ W1,
    const float* __restrict__ b1,
    float* __restrict__ A, float* __restrict__ Bt) {
  const int i = blockIdx.x;
  const int k = threadIdx.x;  // 0..127
  __shared__ float n[D];
  if (k < D) n[k] = node[i * D + k];
  __syncthreads();
  float a = b1[k];
  float b = 0.f;
#pragma unroll
  for (int r = 0; r < D; ++r) {
    const float nv = n[r];
    a = fmaf(nv, W1[r * H + k], a);
    b = fmaf(nv, W1[(D + r) * H + k], b);
  }
  A[i * H + k] = a;
  Bt[k * F + i] = b;
}

// Pair kernel (register-B): thread owns ONE column j, holds B[j][k] k=0..127
// entirely in VGPRs. Block = 256 threads (one j-panel) x 4 rows.
// Inner loop has ZERO global loads: A 4-row panel broadcast from LDS (b128/k),
// w2 quads from LDS. 4 independent gelu chains/thread (rows), pk-paired.
// gelu_tanh(x) = x * rcp(1 + exp2(x * (C1 + C2*x^2)))
// Raw logits written to out; softmax_kernel normalizes in place (row consts
// like b2 cancel there).
#define C1 (-2.3022082f)
#define C2 (-0.10294323f)

__global__ __launch_bounds__(256, 3) void pair_kernel(
    const float* __restrict__ A, const float* __restrict__ Bt,
    const float* __restrict__ w2, float* __restrict__ out) {
  const int tid = threadIdx.x;
  const int jpanel = blockIdx.x & 3;        // 4 panels of 256 columns
  const int rp = blockIdx.x >> 2;           // 256 row-panels of 4 rows
  const int j = jpanel * 256 + tid;
  const int i0 = rp * 4;

  __shared__ float4 sA[H];       // (A[i0..i0+3][k]) per k
  __shared__ float4 sC[H / 4];   // w2 in quads

  if (tid < H)
    sA[tid] = make_float4(A[(i0 + 0) * H + tid], A[(i0 + 1) * H + tid],
                          A[(i0 + 2) * H + tid], A[(i0 + 3) * H + tid]);
  if (tid < H / 4)
    sC[tid] = reinterpret_cast<const float4*>(w2)[tid];

  // B column -> registers (coalesced: consecutive threads, consecutive j)
  float B[H];
#pragma unroll
  for (int k = 0; k < H; ++k) B[k] = Bt[(size_t)k * F + j];
  __syncthreads();

  v2f acc01 = {0.f, 0.f};  // rows i0, i0+1
  v2f acc23 = {0.f, 0.f};  // rows i0+2, i0+3

#pragma unroll
  for (int k4 = 0; k4 < H / 4; ++k4) {
    const float4 c4 = sC[k4];
    const float cc[4] = {c4.x, c4.y, c4.z, c4.w};
#pragma unroll
    for (int t = 0; t < 4; ++t) {
      const int k = k4 * 4 + t;
      const float bk = B[k];
      const float4 a4 = sA[k];
      const float wk = cc[t];
      {
        v2f X = {a4.x + bk, a4.y + bk};
        const v2f U = X * X;
        const v2f P = __builtin_elementwise_fma((v2f)(C2), U, (v2f)(C1));
        const v2f Arg = X * P;
        v2f E;
        E.x = __builtin_amdgcn_exp2f(Arg.x);
        E.y = __builtin_amdgcn_exp2f(Arg.y);
        const v2f Dn = 1.0f + E;
        v2f R;
        R.x = __builtin_amdgcn_rcpf(Dn.x);
        R.y = __builtin_amdgcn_rcpf(Dn.y);
        acc01 = __builtin_elementwise_fma(wk * X, R, acc01);
      }
      {
        v2f X = {a4.z + bk, a4.w + bk};
        const v2f U = X * X;
        const v2f P = __builtin_elementwise_fma((v2f)(C2), U, (v2f)(C1));
        const v2f Arg = X * P;
        v2f E;
        E.x = __builtin_amdgcn_exp2f(Arg.x);
        E.y = __builtin_amdgcn_exp2f(Arg.y);
        const v2f Dn = 1.0f + E;
        v2f R;
        R.x = __builtin_amdgcn_rcpf(Dn.x);
        R.y = __builtin_amdgcn_rcpf(Dn.y);
        acc23 = __builtin_elementwise_fma(wk * X, R, acc23);
      }
    }
  }

  // raw logits -> out (coalesced dword per row)
  out[(size_t)(i0 + 0) * F + j] = acc01.x;
  out[(size_t)(i0 + 1) * F + j] = acc01.y;
  out[(size_t)(i0 + 2) * F + j] = acc23.x;
  out[(size_t)(i0 + 3) * F + j] = acc23.y;
}

// In-place row softmax: block = one row, 256 threads x float4.
__global__ __launch_bounds__(256) void softmax_kernel(float* __restrict__ L) {
  const int i = blockIdx.x;
  const int tid = threadIdx.x;
  const int wave = tid >> 6;
  const int lane = tid & 63;
  __shared__ float redm[4];
  __shared__ float reds[4];

  float4* row = reinterpret_cast<float4*>(L + (size_t)i * F);
  float4 v = row[tid];

  float m = fmaxf(fmaxf(v.x, v.y), fmaxf(v.z, v.w));
#pragma unroll
  for (int off = 32; off >= 1; off >>= 1)
    m = fmaxf(m, __shfl_xor(m, off, 64));
  if (lane == 0) redm[wave] = m;
  __syncthreads();
  m = fmaxf(fmaxf(redm[0], redm[1]), fmaxf(redm[2], redm[3]));

  v.x = __expf(v.x - m);
  v.y = __expf(v.y - m);
  v.z = __expf(v.z - m);
  v.w = __expf(v.w - m);
  float s = v.x + v.y + v.z + v.w;
#pragma unroll
  for (int off = 32; off >= 1; off >>= 1)
    s += __shfl_xor(s, off, 64);
  if (lane == 0) reds[wave] = s;
  __syncthreads();
  s = reds[0] + reds[1] + reds[2] + reds[3];

  const float inv = __builtin_amdgcn_rcpf(s);
  v.x *= inv;
  v.y *= inv;
  v.z *= inv;
  v.w *= inv;
  row[tid] = v;
}

extern "C" void kernel_launch(void* const* d_in, const int* in_sizes, int n_in,
                              void* d_out, int out_size, void* d_ws, size_t ws_size,
                              hipStream_t stream) {
  const float* node = (const float*)d_in[0];  // [1024,64]
  const float* W1   = (const float*)d_in[1];  // [128,128]
  const float* b1   = (const float*)d_in[2];  // [128]
  const float* w2   = (const float*)d_in[3];  // [128]
  // d_in[4] = b2 : cancels in softmax, unused
  float* out = (float*)d_out;                 // [1024,1024]

  float* A  = (float*)d_ws;                   // [1024][128] = 512 KB
  float* Bt = A + (size_t)F * H;              // [128][1024] = 512 KB

  prep_kernel<<<F, H, 0, stream>>>(node, W1, b1, A, Bt);
  pair_kernel<<<(F / 4) * 4, 256, 0, stream>>>(A, Bt, w2, out);
  softmax_kernel<<<F, 256, 0, stream>>>(out);
}

// Round 8
// 44.438 us; speedup vs baseline: 2.3507x; 2.3507x over previous
//
#include <hip/hip_runtime.h>
#include <math.h>

#define F 1024
#define D 64
#define H 128

typedef float v2f __attribute__((ext_vector_type(2)));

// Prep: A[i][k] = sum_r node[i][r]*W1[r][k] + b1[k]
//       Bt[k][i] = sum_r node[i][r]*W1[64+r][k]   (transposed for coalesced hot-loop reads)
__global__ __launch_bounds__(128) void prep_kernel(
    const float* __restrict__ node, const float* __restrict__ W1,
    const float* __restrict__ b1,
    float* __restrict__ A, float* __restrict__ Bt) {
  const int i = blockIdx.x;
  const int k = threadIdx.x;  // 0..127
  __shared__ float n[D];
  if (k < D) n[k] = node[i * D + k];
  __syncthreads();
  float a = b1[k];
  float b = 0.f;
#pragma unroll
  for (int r = 0; r < D; ++r) {
    const float nv = n[r];
    a = fmaf(nv, W1[r * H + k], a);
    b = fmaf(nv, W1[(D + r) * H + k], b);
  }
  A[i * H + k] = a;
  Bt[k * F + i] = b;
}

// Pair kernel: block = 2 output rows (i0, i0+1), 512 threads (8 waves);
// thread owns j = 2*tid, 2*tid+1 packed as v2f (v_pk_* full-rate ops).
// Explicit 1-deep software pipeline: next k's Bt/A loaded into named regs
// before computing current k. launch_bounds(512,2) lifts the VGPR cap so
// the scheduler can keep loads in flight (R6 chose 36 VGPR -> mid-loop
// vmcnt stalls; R7's scratch-spill disaster came from a *3rd-arg* cap, not
// from register prefetching itself).
// gelu_tanh(x) = x * rcp(1 + exp2(x * (C1 + C2*x^2)))
// C1 = -2*sqrt(2/pi)*log2(e), C2 = C1*0.044715.
// logits[i,j] = sum_k w2[k] * gelu(A[i,k] + Bt[k,j]); b2 cancels in softmax.
#define C1 (-2.3022082f)
#define C2 (-0.10294323f)

__device__ __forceinline__ void gelu_acc_pk(float a, v2f b, float wk, v2f& acc) {
  const v2f X = a + b;
  const v2f U = X * X;
  const v2f P = __builtin_elementwise_fma((v2f)(C2), U, (v2f)(C1));
  const v2f Arg = X * P;
  v2f E;
  E.x = __builtin_amdgcn_exp2f(Arg.x);
  E.y = __builtin_amdgcn_exp2f(Arg.y);
  const v2f Dn = 1.0f + E;
  v2f R;
  R.x = __builtin_amdgcn_rcpf(Dn.x);
  R.y = __builtin_amdgcn_rcpf(Dn.y);
  acc = __builtin_elementwise_fma(wk * X, R, acc);
}

__global__ __launch_bounds__(512, 2) void pair_kernel(
    const float* __restrict__ A, const float* __restrict__ Bt,
    const float* __restrict__ w2, float* __restrict__ out) {
  const int i0 = blockIdx.x * 2;
  const int tid = threadIdx.x;

  __shared__ float4 sAW[H];  // (A[i0][k], A[i0+1][k], w2[k], 0)
  __shared__ float redm[8][2];
  __shared__ float reds[8][2];

  if (tid < H)
    sAW[tid] = make_float4(A[i0 * H + tid], A[(i0 + 1) * H + tid], w2[tid], 0.f);
  __syncthreads();

  v2f acc0 = {0.f, 0.f};  // row i0,   j = 2tid, 2tid+1
  v2f acc1 = {0.f, 0.f};  // row i0+1, j = 2tid, 2tid+1

  const v2f* bp = reinterpret_cast<const v2f*>(Bt) + tid;  // Bt[k][2*tid..]

  // ---- software-pipelined k-loop (prefetch depth 1, named regs) ----
  v2f b_c = bp[0];
  float4 aw_c = sAW[0];
#pragma unroll 8
  for (int k = 0; k < H - 1; ++k) {
    const v2f b_n = bp[(k + 1) * (F / 2)];
    const float4 aw_n = sAW[k + 1];
    gelu_acc_pk(aw_c.x, b_c, aw_c.z, acc0);
    gelu_acc_pk(aw_c.y, b_c, aw_c.z, acc1);
    b_c = b_n;
    aw_c = aw_n;
  }
  gelu_acc_pk(aw_c.x, b_c, aw_c.z, acc0);
  gelu_acc_pk(aw_c.y, b_c, aw_c.z, acc1);

  // ---- fused softmax per row (1024 logits each, 8 waves) ----
  const int wave = tid >> 6;
  const int lane = tid & 63;

  float m0 = fmaxf(acc0.x, acc0.y);
  float m1 = fmaxf(acc1.x, acc1.y);
#pragma unroll
  for (int off = 32; off >= 1; off >>= 1) {
    m0 = fmaxf(m0, __shfl_xor(m0, off, 64));
    m1 = fmaxf(m1, __shfl_xor(m1, off, 64));
  }
  if (lane == 0) {
    redm[wave][0] = m0;
    redm[wave][1] = m1;
  }
  __syncthreads();
  m0 = redm[0][0];
  m1 = redm[0][1];
#pragma unroll
  for (int w = 1; w < 8; ++w) {
    m0 = fmaxf(m0, redm[w][0]);
    m1 = fmaxf(m1, redm[w][1]);
  }

  float e00 = __expf(acc0.x - m0);
  float e01 = __expf(acc0.y - m0);
  float e10 = __expf(acc1.x - m1);
  float e11 = __expf(acc1.y - m1);
  float s0 = e00 + e01;
  float s1 = e10 + e11;
#pragma unroll
  for (int off = 32; off >= 1; off >>= 1) {
    s0 += __shfl_xor(s0, off, 64);
    s1 += __shfl_xor(s1, off, 64);
  }
  if (lane == 0) {
    reds[wave][0] = s0;
    reds[wave][1] = s1;
  }
  __syncthreads();
  s0 = 0.f;
  s1 = 0.f;
#pragma unroll
  for (int w = 0; w < 8; ++w) {
    s0 += reds[w][0];
    s1 += reds[w][1];
  }

  const float inv0 = __builtin_amdgcn_rcpf(s0);
  const float inv1 = __builtin_amdgcn_rcpf(s1);
  float2 o0, o1;
  o0.x = e00 * inv0;
  o0.y = e01 * inv0;
  o1.x = e10 * inv1;
  o1.y = e11 * inv1;
  *reinterpret_cast<float2*>(out + (size_t)i0 * F + 2 * tid) = o0;
  *reinterpret_cast<float2*>(out + (size_t)(i0 + 1) * F + 2 * tid) = o1;
}

extern "C" void kernel_launch(void* const* d_in, const int* in_sizes, int n_in,
                              void* d_out, int out_size, void* d_ws, size_t ws_size,
                              hipStream_t stream) {
  const float* node = (const float*)d_in[0];  // [1024,64]
  const float* W1   = (const float*)d_in[1];  // [128,128]
  const float* b1   = (const float*)d_in[2];  // [128]
  const float* w2   = (const float*)d_in[3];  // [128]
  // d_in[4] = b2 : cancels in softmax, unused
  float* out = (float*)d_out;                 // [1024,1024]

  float* A  = (float*)d_ws;                   // [1024][128] = 512 KB
  float* Bt = A + (size_t)F * H;              // [128][1024] = 512 KB

  prep_kernel<<<F, H, 0, stream>>>(node, W1, b1, A, Bt);
  pair_kernel<<<F / 2, 512, 0, stream>>>(A, Bt, w2, out);
}